// Round 10
// baseline (65.092 us; speedup 1.0000x reference)
//
#include <hip/hip_runtime.h>

// Spiking eLIF layer: x (B=64, C=512, T=1024) f32, beta scalar, vth (C,).
//   rst = spk*vth; mem = mem*beta + x[t] - rst; spk = (mem > vth) ? 1 : 0
// Output spk, layout (B, C, T).
//
// R10: attack HBM *granularity*. R6/R8/R9 all converge at ~47-50us with
// 256B-segment x 4KB-stride access (profiled 2.25 TB/s); every slab phase
// touched only residue ch (mod 16) of the 256B-granule space chip-wide.
// Here each VMEM instruction is ONE 1KB CONTIGUOUS burst (64 lanes x 16B in
// a single row segment). Slab = 32 rows x 256 t. Phases cover 4/16 residues.
//
// Kept from R6 (each element empirically validated):
//  - register staging + compiler-scheduled per-register vmcnt (beat
//    global_load_lds DMA with hand-counted vmcnt, R7/R8, and beat
//    sched_barrier pinning, R5).
//  - XOR-swizzled LDS, write side lane-linear by PRE-SWIZZLING the global
//    address: load instr j (row j), lane l reads global vec4 (l ^ (j&7)) =>
//    LDS write slot j*64+l is linear; compute lane l reads row l's vec jt at
//    slot l*64 + (jt ^ (l&7)) -> 8-residue uniform spread = bank floor.
//  - 1 wave per block: no __syncthreads, no vmcnt(0) drain; DS-pipe same-wave
//    ordering makes single-buffered in_lds/out_lds safe.
//
// Correctness: __f*_rn forbids FMA contraction (bit-exact vs numpy fp32; one
// flipped spike corrupts the rest of the row via the reset term).
// (mem > vth) == (fl(mem - vth) > 0) in IEEE RN with gradual underflow.

typedef float f32x4 __attribute__((ext_vector_type(4)));

#define T_LEN 1024
#define C_LEN 512
#define ROWS  32                  // rows per block
#define ROWV  (T_LEN / 4)         // vec4 per row = 256
#define SVEC  64                  // vec4 per row per slab (= 256 t, 1 KB)
#define NCH   (ROWV / SVEC)       // 4 slabs

#define STEP(xv_, sv_)                                 \
    do {                                               \
        float m1_ = __fmul_rn(mem, beta);              \
        float m2_ = __fadd_rn(m1_, (xv_));             \
        mem = __fsub_rn(m2_, rst);                     \
        bool b_ = (mem > vth);                         \
        (sv_) = b_ ? 1.0f : 0.0f;                      \
        rst = b_ ? vth : 0.0f;                         \
    } while (0)

// 32 loads, each 1KB contiguous: instr j = row j's slab segment; lane l
// fetches vec4 (l ^ (j&7)) of the segment (128B-span permutation, still
// fully coalesced). Makes the LDS write below lane-linear.
#define LOADS(ch)                                                          \
    do {                                                                   \
        _Pragma("unroll")                                                  \
        for (int j_ = 0; j_ < ROWS; ++j_)                                  \
            stg[j_] = xv[(size_t)(rb + j_) * ROWV + (ch) * SVEC +          \
                         (l ^ (j_ & 7))];                                  \
    } while (0)

// lane-linear LDS write: slot j*64 + l holds (row j, vec l^(j&7))
#define DSW()                                                              \
    do {                                                                   \
        _Pragma("unroll")                                                  \
        for (int j_ = 0; j_ < ROWS; ++j_)                                  \
            in_lds[64 * j_ + l] = stg[j_];                                 \
    } while (0)

// lane l (<32) scans row l: vec jt at physical slot l*64 + (jt ^ (l&7));
// residues spread uniformly over 8 bank-groups (floor). t ascends with jt.
#define COMPUTE()                                                          \
    do {                                                                   \
        if (l < ROWS) {                                                    \
            _Pragma("unroll")                                              \
            for (int jt_ = 0; jt_ < SVEC; ++jt_) {                         \
                f32x4 v_ = in_lds[l * 64 + (jt_ ^ (l & 7))];               \
                f32x4 s_;                                                  \
                STEP(v_.x, s_.x);                                          \
                STEP(v_.y, s_.y);                                          \
                STEP(v_.z, s_.z);                                          \
                STEP(v_.w, s_.w);                                          \
                out_lds[l * 64 + (jt_ ^ (l & 7))] = s_;                    \
            }                                                              \
        }                                                                  \
    } while (0)

// mirror of LOADS: lane-linear LDS read, 1KB-contiguous store
#define DRAIN(ch)                                                          \
    do {                                                                   \
        _Pragma("unroll")                                                  \
        for (int j_ = 0; j_ < ROWS; ++j_)                                  \
            ov[(size_t)(rb + j_) * ROWV + (ch) * SVEC + (l ^ (j_ & 7))] =  \
                out_lds[64 * j_ + l];                                      \
    } while (0)

__global__ __launch_bounds__(64, 1) void elif_scan_kernel(
    const float* __restrict__ x,
    const float* __restrict__ beta_p,
    const float* __restrict__ vth_p,
    float* __restrict__ out)
{
    __shared__ f32x4 in_lds[ROWS * SVEC];    // 32 KB (single; stg is buffer 2)
    __shared__ f32x4 out_lds[ROWS * SVEC];   // 32 KB

    const int l  = threadIdx.x;              // lane 0..63
    const int rb = blockIdx.x * ROWS;

    const f32x4* __restrict__ xv = (const f32x4*)x;
    f32x4* __restrict__       ov = (f32x4*)out;

    const float beta = beta_p[0];
    const float vth  = vth_p[(rb + (l & (ROWS - 1))) & (C_LEN - 1)];

    f32x4 stg[ROWS];               // staged slab, compile-time indexed only
    float mem = 0.0f;
    float rst = 0.0f;

    // prologue: slab 0 -> LDS; slab 1 loads in flight in stg
    LOADS(0);
    DSW();
    LOADS(1);

    #pragma unroll 1
    for (int ch = 0; ch < NCH; ++ch) {
        // invariant: in_lds holds slab ch; stg holds slab ch+1 (in flight).
        // Same-wave DS ordering: COMPUTE's reads precede next DSW's writes.
        COMPUTE();
        DRAIN(ch);
        if (ch < NCH - 1) DSW();
        if (ch < NCH - 2) LOADS(ch + 2);
    }
}

extern "C" void kernel_launch(void* const* d_in, const int* in_sizes, int n_in,
                              void* d_out, int out_size, void* d_ws, size_t ws_size,
                              hipStream_t stream) {
    const float* x      = (const float*)d_in[0];
    const float* beta_p = (const float*)d_in[1];
    const float* vth_p  = (const float*)d_in[2];
    float* out          = (float*)d_out;

    const int n_rows = in_sizes[0] / T_LEN;      // B*C = 32768
    const int grid   = n_rows / ROWS;            // 1024 blocks, 2/CU resident

    elif_scan_kernel<<<grid, 64, 0, stream>>>(x, beta_p, vth_p, out);
}

// Round 11
// 55.107 us; speedup vs baseline: 1.1812x; 1.1812x over previous
//
#include <hip/hip_runtime.h>

// Spiking eLIF layer: x (B=64, C=512, T=1024) f32, beta scalar, vth (C,).
//   rst = spk*vth; mem = mem*beta + x[t] - rst; spk = (mem > vth) ? 1 : 0
// Output spk, layout (B, C, T).
//
// R11 = R10's granularity probe, decontaminated:
//  - 1KB contiguous per VMEM instr (slab = 32 rows x 256 t; instr j = row
//    j's full 1KB segment), vs R6's 4x256B at 4KB stride.
//  - Conflict-free swizzle with R6's PROVEN bank structure: compute reads
//    slot l*64 + (jt ^ (l&15)) — bank phase (jt^(l&15))%8, identical to
//    R6's measured-zero pattern. R10's (l&7) variant was a 4-way conflict
//    (524K measured) — that, not granularity, caused the regression.
//  - Global pre-swizzle lane l <-> vec (l ^ (j&15)): bijective inside each
//    256B block, so each 1KB burst still covers 16 full lines.
//  - Spike-packing: COMPUTE packs 4 spikes into one u32 in out_pack (8KB);
//    DRAIN expands to f32x4 in registers. LDS total 40KB -> 4 blocks/CU,
//    ALL 1024 blocks co-resident (2x R6's rows/CU), DS traffic -40%.
//  - Register staging + compiler-scheduled vmcnt (beat DMA-counted R7/R8
//    and sched_barrier R5). 1 wave/block: no barriers, no vmcnt(0) drains;
//    same-wave DS-pipe ordering makes single in_lds buffer safe.
//
// Correctness: __f*_rn forbids FMA contraction (bit-exact vs numpy fp32; one
// flipped spike corrupts the rest of the row via the reset term).
// (mem > vth) == (fl(mem - vth) > 0) in IEEE RN with gradual underflow.

typedef float f32x4 __attribute__((ext_vector_type(4)));

#define T_LEN 1024
#define C_LEN 512
#define ROWS  32                  // rows per block (one lane per row, l<32)
#define ROWV  (T_LEN / 4)         // vec4 per row = 256
#define SVEC  64                  // vec4 per row per slab = 256 t = 1 KB
#define NCH   (ROWV / SVEC)       // 4 slabs

#define STEPB(xv_, bb_)                                \
    do {                                               \
        float m1_ = __fmul_rn(mem, beta);              \
        float m2_ = __fadd_rn(m1_, (xv_));             \
        mem = __fsub_rn(m2_, rst);                     \
        bool b_ = (mem > vth);                         \
        (bb_) = b_;                                    \
        rst = b_ ? vth : 0.0f;                         \
    } while (0)

// 32 loads, each 1KB contiguous: instr j = row j's slab segment; lane l
// fetches vec (l ^ (j&15)) — permuted within 256B blocks, still 16 full
// lines. Makes the LDS write below lane-linear.
#define LOADS(ch)                                                          \
    do {                                                                   \
        _Pragma("unroll")                                                  \
        for (int j_ = 0; j_ < ROWS; ++j_)                                  \
            stg[j_] = xv[(size_t)(rb + j_) * ROWV + (ch) * SVEC +          \
                         (l ^ (j_ & 15))];                                 \
    } while (0)

// lane-linear LDS write: slot j*64 + l holds (row j, vec l^(j&15))
#define DSW()                                                              \
    do {                                                                   \
        _Pragma("unroll")                                                  \
        for (int j_ = 0; j_ < ROWS; ++j_)                                  \
            in_lds[64 * j_ + l] = stg[j_];                                 \
    } while (0)

// lane l (<32) scans row l: vec jt at slot l*64 + (jt ^ (l&15));
// bank phase (jt^(l&15))%8 == R6's measured-conflict-free structure.
// 4 spikes packed into one u32 -> out_pack (b32 writes, 2-way = free).
#define COMPUTE()                                                          \
    do {                                                                   \
        if (l < ROWS) {                                                    \
            _Pragma("unroll")                                              \
            for (int jt_ = 0; jt_ < SVEC; ++jt_) {                         \
                f32x4 v_ = in_lds[l * 64 + (jt_ ^ (l & 15))];              \
                bool b0_, b1_, b2_, b3_;                                   \
                STEPB(v_.x, b0_);                                          \
                STEPB(v_.y, b1_);                                          \
                STEPB(v_.z, b2_);                                          \
                STEPB(v_.w, b3_);                                          \
                out_pack[l * 64 + (jt_ ^ (l & 15))] =                      \
                    (unsigned)b0_ | ((unsigned)b1_ << 1) |                 \
                    ((unsigned)b2_ << 2) | ((unsigned)b3_ << 3);           \
            }                                                              \
        }                                                                  \
    } while (0)

// mirror of LOADS: b32 LDS read (lanes 0..63 -> consecutive slots, 2-way
// free), expand 4 bits -> f32x4 in registers, 1KB-contiguous store.
#define DRAIN(ch)                                                          \
    do {                                                                   \
        _Pragma("unroll")                                                  \
        for (int j_ = 0; j_ < ROWS; ++j_) {                                \
            const unsigned pk_ = out_pack[64 * j_ + l];                    \
            f32x4 s_;                                                      \
            s_.x = (pk_ & 1u) ? 1.0f : 0.0f;                               \
            s_.y = (pk_ & 2u) ? 1.0f : 0.0f;                               \
            s_.z = (pk_ & 4u) ? 1.0f : 0.0f;                               \
            s_.w = (pk_ & 8u) ? 1.0f : 0.0f;                               \
            ov[(size_t)(rb + j_) * ROWV + (ch) * SVEC + (l ^ (j_ & 15))] = \
                s_;                                                        \
        }                                                                  \
    } while (0)

__global__ __launch_bounds__(64, 1) void elif_scan_kernel(
    const float* __restrict__ x,
    const float* __restrict__ beta_p,
    const float* __restrict__ vth_p,
    float* __restrict__ out)
{
    __shared__ f32x4 in_lds[ROWS * SVEC];       // 32 KB
    __shared__ unsigned out_pack[ROWS * SVEC];  // 8 KB  (total 40 KB -> 4/CU)

    const int l  = threadIdx.x;                 // lane 0..63
    const int rb = blockIdx.x * ROWS;

    const f32x4* __restrict__ xv = (const f32x4*)x;
    f32x4* __restrict__       ov = (f32x4*)out;

    const float beta = beta_p[0];
    const float vth  = vth_p[(rb + (l & (ROWS - 1))) & (C_LEN - 1)];

    f32x4 stg[ROWS];               // staged slab, compile-time indexed only
    float mem = 0.0f;
    float rst = 0.0f;

    // prologue: slab 0 -> LDS; slab 1 loads in flight in stg
    LOADS(0);
    DSW();
    LOADS(1);

    #pragma unroll 1
    for (int ch = 0; ch < NCH; ++ch) {
        // invariant: in_lds holds slab ch; stg holds slab ch+1 (in flight).
        // Same-wave DS ordering: COMPUTE's reads precede next DSW's writes.
        COMPUTE();
        DRAIN(ch);
        if (ch < NCH - 1) DSW();
        if (ch < NCH - 2) LOADS(ch + 2);
    }
}

extern "C" void kernel_launch(void* const* d_in, const int* in_sizes, int n_in,
                              void* d_out, int out_size, void* d_ws, size_t ws_size,
                              hipStream_t stream) {
    const float* x      = (const float*)d_in[0];
    const float* beta_p = (const float*)d_in[1];
    const float* vth_p  = (const float*)d_in[2];
    float* out          = (float*)d_out;

    const int n_rows = in_sizes[0] / T_LEN;      // B*C = 32768
    const int grid   = n_rows / ROWS;            // 1024 blocks, 4/CU resident

    elif_scan_kernel<<<grid, 64, 0, stream>>>(x, beta_p, vth_p, out);
}

// Round 12
// 54.062 us; speedup vs baseline: 1.2040x; 1.0193x over previous
//
#include <hip/hip_runtime.h>

// Spiking eLIF layer: x (B=64, C=512, T=1024) f32, beta scalar, vth (C,).
//   rst = spk*vth; mem = mem*beta + x[t] - rst; spk = (mem > vth) ? 1 : 0
// Output spk, layout (B, C, T).
//
// R12: clean granularity A/B vs R6. ONLY change: 512B contiguous segments
// per VMEM instr (SVEC=32, each instr = 2 rows x 512B) vs R6's 4 rows x
// 256B. Everything else identical to the 47.3us R6 anchor: 64 rows/block,
// full 64-lane compute, register staging + compiler-scheduled vmcnt (beat
// DMA R7/R8, sched_barrier R5), proven conflict-free swizzle family,
// 1 wave/block (no barriers, no vmcnt(0) drains). Single-buffered in_lds
// (stg is the 2nd buffer; same-wave DS ordering, validated R10/R11) keeps
// LDS at 64KB -> 2 blocks/CU (= R6 occupancy).
//
// Swizzle (derived, same family as R6's measured-zero pattern):
//  - load: lane l, instr j: row r=2j+(l>>5), global vec v=(l&31)^(r&15)
//    -> LDS write slot r*32+(l&31): lane-linear, bank phase l%8 (0-conf).
//  - compute: lane l scans row l; vec jt at slot l*32+(jt^(l&15)):
//    phase (jt%8)^(l%8), distinct across phase lanes (0-conf).
//  - slot r*32+p holds vec p^(r&15); DRAIN mirrors the load mapping.
// R11 lesson folded in: no half-masked compute, no packing (those, plus a
// 2-way pack-write conflict, caused R11's regression — not granularity).
//
// Correctness: __f*_rn forbids FMA contraction (bit-exact vs numpy fp32; one
// flipped spike corrupts the rest of the row via the reset term).
// (mem > vth) == (fl(mem - vth) > 0) in IEEE RN with gradual underflow.

typedef float f32x4 __attribute__((ext_vector_type(4)));

#define T_LEN 1024
#define C_LEN 512
#define ROWS  64                  // rows per block (= lanes, all active)
#define ROWV  (T_LEN / 4)         // vec4 per row = 256
#define SVEC  32                  // vec4 per row per slab = 128 t = 512 B
#define NCH   (ROWV / SVEC)       // 8 slabs
#define NLD   ((ROWS * SVEC) / 64) // 32 VMEM instrs per slab

#define STEP(xv_, sv_)                                 \
    do {                                               \
        float m1_ = __fmul_rn(mem, beta);              \
        float m2_ = __fadd_rn(m1_, (xv_));             \
        mem = __fsub_rn(m2_, rst);                     \
        bool b_ = (mem > vth);                         \
        (sv_) = b_ ? 1.0f : 0.0f;                      \
        rst = b_ ? vth : 0.0f;                         \
    } while (0)

// 32 loads/slab: instr j = rows 2j, 2j+1 (512B contiguous each); lane l
// fetches vec (l&31)^(r&15) of row r=2j+(l>>5). Pre-swizzled so the LDS
// write below is lane-linear.
#define LOADS(ch)                                                          \
    do {                                                                   \
        _Pragma("unroll")                                                  \
        for (int j_ = 0; j_ < NLD; ++j_) {                                 \
            const int r_ = 2 * j_ + (l >> 5);                              \
            const int v_ = (l & 31) ^ (r_ & 15);                           \
            stg[j_] = xv[(size_t)(rb + r_) * ROWV + (ch) * SVEC + v_];     \
        }                                                                  \
    } while (0)

// lane-linear LDS write: slot r*32 + (l&31) holds (row r, vec (l&31)^(r&15))
#define DSW()                                                              \
    do {                                                                   \
        _Pragma("unroll")                                                  \
        for (int j_ = 0; j_ < NLD; ++j_) {                                 \
            const int r_ = 2 * j_ + (l >> 5);                              \
            in_lds[r_ * 32 + (l & 31)] = stg[j_];                          \
        }                                                                  \
    } while (0)

// lane l scans row l: vec jt at slot l*32 + (jt^(l&15)); writes spikes to
// the same slot of out_lds. Bank phase (jt%8)^(l%8): conflict-free.
#define COMPUTE()                                                          \
    do {                                                                   \
        _Pragma("unroll")                                                  \
        for (int jt_ = 0; jt_ < SVEC; ++jt_) {                             \
            f32x4 v_ = in_lds[l * 32 + (jt_ ^ (l & 15))];                  \
            f32x4 s_;                                                      \
            STEP(v_.x, s_.x);                                              \
            STEP(v_.y, s_.y);                                              \
            STEP(v_.z, s_.z);                                              \
            STEP(v_.w, s_.w);                                              \
            out_lds[l * 32 + (jt_ ^ (l & 15))] = s_;                       \
        }                                                                  \
    } while (0)

// mirror of LOADS: lane-linear LDS read, 512B-contiguous stores
#define DRAIN(ch)                                                          \
    do {                                                                   \
        _Pragma("unroll")                                                  \
        for (int j_ = 0; j_ < NLD; ++j_) {                                 \
            const int r_ = 2 * j_ + (l >> 5);                              \
            const int v_ = (l & 31) ^ (r_ & 15);                           \
            ov[(size_t)(rb + r_) * ROWV + (ch) * SVEC + v_] =              \
                out_lds[r_ * 32 + (l & 31)];                               \
        }                                                                  \
    } while (0)

__global__ __launch_bounds__(64, 1) void elif_scan_kernel(
    const float* __restrict__ x,
    const float* __restrict__ beta_p,
    const float* __restrict__ vth_p,
    float* __restrict__ out)
{
    __shared__ f32x4 in_lds[ROWS * SVEC];     // 32 KB (stg is buffer 2)
    __shared__ f32x4 out_lds[ROWS * SVEC];    // 32 KB  (total 64 KB -> 2/CU)

    const int l  = threadIdx.x;               // lane 0..63
    const int rb = blockIdx.x * ROWS;

    const f32x4* __restrict__ xv = (const f32x4*)x;
    f32x4* __restrict__       ov = (f32x4*)out;

    const float beta = beta_p[0];
    const float vth  = vth_p[(rb + l) & (C_LEN - 1)];

    f32x4 stg[NLD];                // staged slab, compile-time indexed only
    float mem = 0.0f;
    float rst = 0.0f;

    // prologue: slab 0 -> LDS; slab 1 loads in flight in stg
    LOADS(0);
    DSW();
    LOADS(1);

    #pragma unroll 1
    for (int ch = 0; ch < NCH; ++ch) {
        // invariant: in_lds holds slab ch; stg holds slab ch+1 (in flight).
        // Same-wave DS ordering: COMPUTE's reads precede next DSW's writes.
        COMPUTE();
        DRAIN(ch);
        if (ch < NCH - 1) DSW();
        if (ch < NCH - 2) LOADS(ch + 2);
    }
}

extern "C" void kernel_launch(void* const* d_in, const int* in_sizes, int n_in,
                              void* d_out, int out_size, void* d_ws, size_t ws_size,
                              hipStream_t stream) {
    const float* x      = (const float*)d_in[0];
    const float* beta_p = (const float*)d_in[1];
    const float* vth_p  = (const float*)d_in[2];
    float* out          = (float*)d_out;

    const int n_rows = in_sizes[0] / T_LEN;      // B*C = 32768
    const int grid   = n_rows / ROWS;            // 512 blocks, 2/CU resident

    elif_scan_kernel<<<grid, 64, 0, stream>>>(x, beta_p, vth_p, out);
}

// Round 13
// 47.037 us; speedup vs baseline: 1.3838x; 1.1494x over previous
//
#include <hip/hip_runtime.h>

// Spiking eLIF layer: x (B=64, C=512, T=1024) f32, beta scalar, vth (C,).
//   rst = spk*vth; mem = mem*beta + x[t] - rst; spk = (mem > vth) ? 1 : 0
// Output spk, layout (B, C, T).
//
// R13 = R6 (the 47.3us anchor: all later structural probes — DMA depth,
// TLP, granularity, packing — were flat or negative) + ONE change:
// nontemporal DRAIN stores. Rationale: input(128MB)+output(128MB) = 256MB
// = L3 exactly; FETCH_SIZE=65.6MB shows output write-allocation evicts
// half the input per pass. nt stores skip L3 allocation -> input stays
// fully L3-resident across replays -> DRAM serves only the write stream.
// R2's NT write-amplification does NOT apply: these stores are fully
// coalesced (4 x 256B contiguous segments per instr — every 64B line
// completely covered), unlike R2's 16B/lane at 4KB stride.
// Tripwire: WRITE_SIZE must stay ~131MB; if it amplifies, revert to R6.
//
// Structure (R6, proven):
//  - 1 wave per block = 64 consecutive rows; slab = 64 t-steps.
//  - coalesced global access via LDS transpose; XOR swizzle
//    (pcol = j ^ (row&15)) applied by PRE-SWIZZLING the global address;
//    LDS writes lane-linear; bank conflicts measured 0.
//  - register staging + compiler-scheduled vmcnt (beat counted-vmcnt DMA
//    and sched_barrier pinning empirically).
//  - single wave per block: no __syncthreads, no vmcnt(0) drains.
//
// Correctness: __f*_rn forbids FMA contraction (bit-exact vs numpy fp32;
// one flipped spike corrupts the rest of the row via the reset term).
// (mem > vth) == (fl(mem - vth) > 0) in IEEE RN with gradual underflow.

typedef float f32x4 __attribute__((ext_vector_type(4)));

#define T_LEN   1024
#define C_LEN   512
#define RPB     64                // rows per block (= lanes per wave)
#define VECS    16                // f32x4 per row per slab (64 floats)
#define NCH     (T_LEN / (VECS * 4)) // 16 slabs
#define ROWV    (T_LEN / 4)       // row stride in f32x4 = 256

#define STEP(xv_, sv_)                                 \
    do {                                               \
        float m1_ = __fmul_rn(mem, beta);              \
        float m2_ = __fadd_rn(m1_, (xv_));             \
        mem = __fsub_rn(m2_, rst);                     \
        bool b_ = (mem > vth);                         \
        (sv_) = b_ ? 1.0f : 0.0f;                      \
        rst = b_ ? vth : 0.0f;                         \
    } while (0)

// 16 coalesced loads: instr j covers rows 4j..4j+3, 16 contiguous lanes per
// row; global col is pre-swizzled so the LDS write below is lane-linear.
#define LOADS(ch)                                                         \
    do {                                                                  \
        _Pragma("unroll")                                                 \
        for (int j_ = 0; j_ < VECS; ++j_) {                               \
            const int rj_ = 4 * j_ + l4;                                  \
            const int gc_ = c16 ^ (rj_ & 15);                             \
            stg[j_] = xv[(size_t)(rb + rj_) * ROWV + (ch) * VECS + gc_];  \
        }                                                                 \
    } while (0)

// lane-linear LDS write: slot 64j + l == [row rj][pcol c16]
#define DSW(buf)                                                          \
    do {                                                                  \
        _Pragma("unroll")                                                 \
        for (int j_ = 0; j_ < VECS; ++j_)                                 \
            in_lds[buf][64 * j_ + l] = stg[j_];                           \
    } while (0)

// lane l scans its own row l: logical col j at physical slot l*16+(j^c16)
#define COMPUTE(buf)                                                      \
    do {                                                                  \
        _Pragma("unroll")                                                 \
        for (int j_ = 0; j_ < VECS; ++j_) {                               \
            f32x4 v_ = in_lds[buf][l * VECS + (j_ ^ c16)];                \
            f32x4 s_;                                                     \
            STEP(v_.x, s_.x);                                             \
            STEP(v_.y, s_.y);                                             \
            STEP(v_.z, s_.z);                                             \
            STEP(v_.w, s_.w);                                             \
            out_lds[l * VECS + (j_ ^ c16)] = s_;                          \
        }                                                                 \
    } while (0)

// mirror of LOADS: lane-linear LDS read, coalesced NONTEMPORAL store
// (full-line coverage: 4 x 256B contiguous segments per instruction).
#define DRAIN(ch)                                                         \
    do {                                                                  \
        _Pragma("unroll")                                                 \
        for (int j_ = 0; j_ < VECS; ++j_) {                               \
            const int rj_ = 4 * j_ + l4;                                  \
            const int gc_ = c16 ^ (rj_ & 15);                             \
            __builtin_nontemporal_store(                                  \
                out_lds[64 * j_ + l],                                     \
                ov + (size_t)(rb + rj_) * ROWV + (ch) * VECS + gc_);      \
        }                                                                 \
    } while (0)

__global__ __launch_bounds__(64, 1) void elif_scan_kernel(
    const float* __restrict__ x,
    const float* __restrict__ beta_p,
    const float* __restrict__ vth_p,
    float* __restrict__ out)
{
    __shared__ f32x4 in_lds[2][RPB * VECS];   // 2 x 16 KB, double-buffered
    __shared__ f32x4 out_lds[RPB * VECS];     // 16 KB

    const int l   = threadIdx.x;   // lane 0..63
    const int l4  = l >> 4;        // 0..3
    const int c16 = l & 15;        // 0..15
    const int rb  = blockIdx.x * RPB;

    const f32x4* __restrict__ xv = (const f32x4*)x;
    f32x4* __restrict__       ov = (f32x4*)out;

    const float beta = beta_p[0];
    const float vth  = vth_p[(rb + l) & (C_LEN - 1)];

    f32x4 stg[VECS];               // staged slab (compile-time indexed only)
    float mem = 0.0f;
    float rst = 0.0f;

    // prologue: slab 0 into in_lds[0]; slab 1 loads in flight
    LOADS(0);
    DSW(0);
    LOADS(1);

    #pragma unroll 1
    for (int ch = 0; ch < NCH; ++ch) {
        // invariant: in_lds[ch&1] holds slab ch; stg holds slab ch+1 (in flight)
        COMPUTE(ch & 1);
        DRAIN(ch);
        if (ch < NCH - 1) DSW((ch + 1) & 1);   // vmcnt wait hidden under compute+drain
        if (ch < NCH - 2) LOADS(ch + 2);       // issue next slab
    }
}

extern "C" void kernel_launch(void* const* d_in, const int* in_sizes, int n_in,
                              void* d_out, int out_size, void* d_ws, size_t ws_size,
                              hipStream_t stream) {
    const float* x      = (const float*)d_in[0];
    const float* beta_p = (const float*)d_in[1];
    const float* vth_p  = (const float*)d_in[2];
    float* out          = (float*)d_out;

    const int n_rows = in_sizes[0] / T_LEN;      // B*C = 32768
    const int grid   = n_rows / RPB;             // 512 blocks -> 2 per CU

    elif_scan_kernel<<<grid, 64, 0, stream>>>(x, beta_p, vth_p, out);
}